// Round 18
// baseline (101.553 us; speedup 1.0000x reference)
//
#include <hip/hip_runtime.h>
#include <stdint.h>

// out[b,c] = <x_b/||x_b||, a_c/||a_c||>, B=16384, C=2048, D=1024, fp32 in/out.
// R18: INT8 GEMM with B DIRECT FROM L2 (halve the LDS pipe, the measured floor)
//   + NONTEMPORAL C stores (the fix for R15's failure mode: C-write streams
//   were evicting the B panel from L2).
//   Pass 1 (R16): per-row amax+sumsq; q=round(127x/amax) i8; s=amax/(127||x||).
//   Pass 2: 256x256 tile, 8 waves (2Mx4N), BK=128 i8, NKT=8. A-only LDS
//   (2x32KB dbuf, row&7 XOR swizzle, 0 conflicts). B: bn CONSTANT PER XCD ->
//   panel = 256x1024 i8 = 256 KB (6% of L2), loaded per-wave global->reg
//   (compiler-managed waits); C stored with __builtin_nontemporal_store so
//   the 134 MB write stream does not evict B. Per tile: stage A(t+1) 4 DMA
//   -> 8 B gather-loads -> 16 A ds_read_b128 -> 64 mfma_i32_16x16x64_i8 ->
//   vmcnt(0) (in-order retirement: only old A-DMAs left) -> barrier.
//   Race rule: stage targets the region whose readers all passed the previous
//   barrier; boundary is vmcnt -> barrier -> read.
//   Regs: acc 128 + A-frag 64 + B-frag 32 + addr ~ 245 < 256 (no spill).

#define D_DIM 1024
#define N_DIM 2048
#define BMt 256
#define BNt 256
#define BKt 128     // i8 per K-tile (128 B rows)
#define NKT 8       // D_DIM / BKt

typedef int i32x4 __attribute__((ext_vector_type(4)));

__global__ __launch_bounds__(256) void quant_rows(
        const float* __restrict__ x, const float* __restrict__ a,
        signed char* __restrict__ xq, signed char* __restrict__ aq,
        float* __restrict__ sx, float* __restrict__ sa, int Bn) {
    const int blk = blockIdx.x;
    const float* in   = (blk < Bn) ? x : a;
    signed char* outq = (blk < Bn) ? xq : aq;
    float* outs       = (blk < Bn) ? sx : sa;
    const int row = (blk < Bn) ? blk : blk - Bn;
    const int t = threadIdx.x;
    const float4 v = ((const float4*)(in + (size_t)row * D_DIM))[t];
    float ss = v.x * v.x + v.y * v.y + v.z * v.z + v.w * v.w;
    float mx = fmaxf(fmaxf(fabsf(v.x), fabsf(v.y)), fmaxf(fabsf(v.z), fabsf(v.w)));
#pragma unroll
    for (int o = 1; o < 64; o <<= 1) {
        ss += __shfl_xor(ss, o);
        mx = fmaxf(mx, __shfl_xor(mx, o));
    }
    __shared__ float redS[4], redM[4];
    if ((t & 63) == 0) { redS[t >> 6] = ss; redM[t >> 6] = mx; }
    __syncthreads();
    const float tot  = redS[0] + redS[1] + redS[2] + redS[3];
    const float amax = fmaxf(fmaxf(redM[0], redM[1]), fmaxf(redM[2], redM[3]));
    const float inv  = (amax > 0.0f) ? (127.0f / amax) : 0.0f;
    int q0 = __float2int_rn(v.x * inv), q1 = __float2int_rn(v.y * inv);
    int q2 = __float2int_rn(v.z * inv), q3 = __float2int_rn(v.w * inv);
    q0 = min(127, max(-127, q0)); q1 = min(127, max(-127, q1));
    q2 = min(127, max(-127, q2)); q3 = min(127, max(-127, q3));
    char4 o; o.x = (char)q0; o.y = (char)q1; o.z = (char)q2; o.w = (char)q3;
    ((char4*)(outq + (size_t)row * D_DIM))[t] = o;
    if (t == 0) outs[row] = amax / (127.0f * fmaxf(sqrtf(tot), 1e-8f));
}

__device__ __forceinline__ void gload_lds16(const void* g, void* l) {
    __builtin_amdgcn_global_load_lds(
        (const __attribute__((address_space(1))) void*)g,
        (__attribute__((address_space(3))) void*)l,
        16, 0, 0);
}

#define BAR()     asm volatile("s_barrier" ::: "memory")
#define VMCNT0()  asm volatile("s_waitcnt vmcnt(0)" ::: "memory")

// LDS (64 KiB): A[p] at p*32768, [256 rows][128 i8], 8 x 16B slots/row,
// slot ^= row&7 (0-conflict, R6-proven geometry).
template<int P, bool STAGE>
__device__ __forceinline__ void ktile(
        int t,
        const signed char* __restrict__ sA,     // A + rowA0*D + voff (per-lane)
        const signed char* const (&bBase)[4],   // per-lane B row bases (L2)
        char* lds0, int dstW,                   // wid*1024 (byte)
        const char* const (&pA)[2][2],
        i32x4 (&acc)[8][4])
{
    // ---- stage A(t+1) into parity P^1 (4 DMA, earliest issue) ----
    if constexpr (STAGE) {
        const int k1 = (t + 1) * BKt;
#pragma unroll
        for (int j = 0; j < 2; ++j) {
            gload_lds16(sA + (size_t)(j * 64) * D_DIM + k1,
                        lds0 + (P ^ 1) * 32768 + j * 8192 + dstW);
            gload_lds16(sA + (size_t)(128 + j * 64) * D_DIM + k1,
                        lds0 + (P ^ 1) * 32768 + 16384 + j * 8192 + dstW);
        }
    }

    // ---- B fragments: 8 global loads (L2-resident panel) ----
    i32x4 bf[4][2];
#pragma unroll
    for (int n = 0; n < 4; ++n)
#pragma unroll
        for (int kk = 0; kk < 2; ++kk)
            bf[n][kk] = *(const i32x4*)(bBase[n] + t * BKt + kk * 64);

    // ---- A fragments: 16 conflict-free ds_read_b128 (parity P) ----
    i32x4 af[8][2];
#pragma unroll
    for (int m = 0; m < 8; ++m)
#pragma unroll
        for (int kk = 0; kk < 2; ++kk)
            af[m][kk] = *(const i32x4*)(pA[P][kk] + m * 2048);

    // ---- 64 MFMA i8 K=64 ----
    __builtin_amdgcn_s_setprio(1);
#pragma unroll
    for (int m = 0; m < 8; ++m)
#pragma unroll
        for (int n = 0; n < 4; ++n)
#pragma unroll
            for (int kk = 0; kk < 2; ++kk)
                acc[m][n] = __builtin_amdgcn_mfma_i32_16x16x64_i8(
                    af[m][kk], bf[n][kk], acc[m][n], 0, 0, 0);
    __builtin_amdgcn_s_setprio(0);

    if constexpr (STAGE) {
        VMCNT0();   // in-order retirement: only my old A-DMAs can remain
        BAR();      // all waves' A landed -> next tile may read (race rule)
    }
}

__global__ __launch_bounds__(512, 2) void gemm256(
        const signed char* __restrict__ A,
        const signed char* __restrict__ Bm,
        const float* __restrict__ sx,
        const float* __restrict__ sb,
        float* __restrict__ Cg)
{
    __shared__ char lds0[65536];  // 64 KiB: A double buffer only

    // bn CONSTANT PER XCD: XCD x -> wg in [64x, 64x+64) -> bn = x (B panel/L2)
    const int nwg = gridDim.x;          // 512
    const int cpx = nwg >> 3;           // 64
    const int wg  = ((int)blockIdx.x & 7) * cpx + ((int)blockIdx.x >> 3);
    const int bn  = wg >> 6;            // 0..7
    const int bm  = wg & 63;            // 0..63
    const int rowA0 = bm * BMt;
    const int rowB0 = bn * BNt;

    const int tid  = threadIdx.x;
    const int lane = tid & 63;
    const int wid  = tid >> 6;          // 0..7
    const int wr   = wid >> 2;          // 0..1 -> 128-row half
    const int wc   = wid & 3;           // 0..3 -> 64-col slice
    const int rl = lane & 15, ts = lane >> 4, r7 = rl & 7;

    // per-lane A frag base ptrs (row&7 == rl&7; kk=1 slot = 4^(ts^r7))
    const int swz0 = ((ts ^ r7) << 4);
    const int swz1 = (((4 + ts) ^ r7) << 4);
    const int aRow = (wr * 128 + rl) * 128;
    const char* pA[2][2];
#pragma unroll
    for (int p = 0; p < 2; ++p) {
        pA[p][0] = lds0 + p * 32768 + aRow + swz0;
        pA[p][1] = lds0 + p * 32768 + aRow + swz1;
    }

    // per-lane B global bases: row = rowB0 + wc*64 + n*16 + rl, k base ts*16
    const signed char* bBase[4];
#pragma unroll
    for (int n = 0; n < 4; ++n)
        bBase[n] = Bm + (size_t)(rowB0 + wc * 64 + n * 16 + rl) * D_DIM + ts * 16;

    // A staging bases (source pre-swizzled; 16 i8 per slot)
    const int gcol = (((tid & 7) ^ ((tid >> 3) & 7)) << 4);
    const int grow = (tid >> 3);
    const signed char* sA = A + (size_t)(rowA0 + grow) * D_DIM + gcol;
    const int dstW = wid * 1024;

    i32x4 acc[8][4] = {};

    // prologue: stage A(0) (parity 0); vmcnt(0) -> barrier
#pragma unroll
    for (int j = 0; j < 2; ++j) {
        gload_lds16(sA + (size_t)(j * 64) * D_DIM,       lds0 + j * 8192 + dstW);
        gload_lds16(sA + (size_t)(128 + j * 64) * D_DIM, lds0 + 16384 + j * 8192 + dstW);
    }
    VMCNT0();
    BAR();

#pragma unroll 1
    for (int t = 0; t < NKT - 2; t += 2) {
        ktile<0, true>(t,     sA, bBase, lds0, dstW, pA, acc);
        ktile<1, true>(t + 1, sA, bBase, lds0, dstW, pA, acc);
    }
    ktile<0, true >(NKT - 2, sA, bBase, lds0, dstW, pA, acc);
    ktile<1, false>(NKT - 1, sA, bBase, lds0, dstW, pA, acc);

    // epilogue: C/D col=lane&15, row=(lane>>4)*4+j (dtype-independent);
    // NONTEMPORAL stores keep the 134 MB C stream out of L2 (B stays resident)
    const int crow0 = rowA0 + wr * 128 + ts * 4;
    const int ccol0 = rowB0 + wc * 64 + rl;
    float sbv[4];
#pragma unroll
    for (int n = 0; n < 4; ++n) sbv[n] = sb[ccol0 + n * 16];
#pragma unroll
    for (int m = 0; m < 8; ++m)
#pragma unroll
        for (int j = 0; j < 4; ++j) {
            const int row = crow0 + m * 16 + j;
            const float sav = sx[row];
#pragma unroll
            for (int n = 0; n < 4; ++n)
                __builtin_nontemporal_store(
                    (float)acc[m][n][j] * sav * sbv[n],
                    &Cg[(size_t)row * N_DIM + ccol0 + n * 16]);
        }
}

extern "C" void kernel_launch(void* const* d_in, const int* in_sizes, int n_in,
                              void* d_out, int out_size, void* d_ws, size_t ws_size,
                              hipStream_t stream) {
    const float* x = (const float*)d_in[0];   // [B, D]
    const float* a = (const float*)d_in[1];   // [C, D]
    float* out = (float*)d_out;               // [B, C]

    const int Bn = in_sizes[0] / D_DIM;  // 16384
    const int Cn = in_sizes[1] / D_DIM;  // 2048

    signed char* xq = (signed char*)d_ws;                      // [B][D] i8
    signed char* aq = xq + (size_t)Bn * D_DIM;                 // [C][D] i8
    float* sx = (float*)(aq + (size_t)Cn * D_DIM);             // [B] f32
    float* sa = sx + Bn;                                       // [C] f32

    quant_rows<<<Bn + Cn, 256, 0, stream>>>(x, a, xq, aq, sx, sa, Bn);

    const int grid = (Bn / BMt) * (Cn / BNt);  // 64 * 8 = 512
    gemm256<<<grid, 512, 0, stream>>>(xq, aq, sx, sa, out);
}

// Round 19
// 88.039 us; speedup vs baseline: 1.1535x; 1.1535x over previous
//
#include <hip/hip_runtime.h>
#include <stdint.h>

// out[b,c] = <x_b/||x_b||, a_c/||a_c||>, B=16384, C=2048, D=1024, fp32 in/out.
// R19: INT8 GEMM (R16 structure) + PERSISTENT 2-TILE BLOCKS.
//   Pass 1 (R16): per-row amax+sumsq; q=round(127x/amax) i8; s=amax/(127||x||).
//   Pass 2: grid 256 (1 block/CU). Block -> tiles (bm,bn1) then (bm,bn1+1):
//   same A panel (tile2 A-stages L2-hot), B col-pair L2-resident per XCD.
//   256x256 tile, 8 waves, BK=128 i8, dbuf LDS 128 KiB, R16's free-run
//   K-tile (stage 8 DMA -> 24 ds_read_b128 (0-conflict row&7 XOR swizzle) ->
//   64 mfma_i32_16x16x64_i8 -> vmcnt(0) -> BAR).
//   BRIDGE (tile1 t7): reads -> lgkm0 -> BAR (all waves' LDS reads drained)
//   -> pre-stage tile2 k0->p0, k1->p1 (16 DMAs, BEFORE the stores) -> MFMA
//   -> tile1 C-stores -> vmcnt(63) (in-order retirement: <=63 outstanding
//   proves the 16 older DMAs landed; HW caps outstanding at 63) -> BAR.
//   Tile2 t0: BAR-only boundary (k1 already proven); t1+: standard. The 67MB
//   store burst drains to HBM UNDER tile2's K-loop (L2 absorbs, fetches are
//   L2-hits) instead of serializing between grid rounds (R16's ~10us x1).
//   Race rule everywhere: stage targets a region whose readers all passed
//   the previous barrier; cross-wave read-ahead behind vmcnt -> BAR -> read.

#define D_DIM 1024
#define N_DIM 2048
#define BMt 256
#define BNt 256
#define BKt 128     // i8 per K-tile (128 B rows)
#define NKT 8       // D_DIM / BKt

typedef int i32x4 __attribute__((ext_vector_type(4)));

__global__ __launch_bounds__(256) void quant_rows(
        const float* __restrict__ x, const float* __restrict__ a,
        signed char* __restrict__ xq, signed char* __restrict__ aq,
        float* __restrict__ sx, float* __restrict__ sa, int Bn) {
    const int blk = blockIdx.x;
    const float* in   = (blk < Bn) ? x : a;
    signed char* outq = (blk < Bn) ? xq : aq;
    float* outs       = (blk < Bn) ? sx : sa;
    const int row = (blk < Bn) ? blk : blk - Bn;
    const int t = threadIdx.x;
    const float4 v = ((const float4*)(in + (size_t)row * D_DIM))[t];
    float ss = v.x * v.x + v.y * v.y + v.z * v.z + v.w * v.w;
    float mx = fmaxf(fmaxf(fabsf(v.x), fabsf(v.y)), fmaxf(fabsf(v.z), fabsf(v.w)));
#pragma unroll
    for (int o = 1; o < 64; o <<= 1) {
        ss += __shfl_xor(ss, o);
        mx = fmaxf(mx, __shfl_xor(mx, o));
    }
    __shared__ float redS[4], redM[4];
    if ((t & 63) == 0) { redS[t >> 6] = ss; redM[t >> 6] = mx; }
    __syncthreads();
    const float tot  = redS[0] + redS[1] + redS[2] + redS[3];
    const float amax = fmaxf(fmaxf(redM[0], redM[1]), fmaxf(redM[2], redM[3]));
    const float inv  = (amax > 0.0f) ? (127.0f / amax) : 0.0f;
    int q0 = __float2int_rn(v.x * inv), q1 = __float2int_rn(v.y * inv);
    int q2 = __float2int_rn(v.z * inv), q3 = __float2int_rn(v.w * inv);
    q0 = min(127, max(-127, q0)); q1 = min(127, max(-127, q1));
    q2 = min(127, max(-127, q2)); q3 = min(127, max(-127, q3));
    char4 o; o.x = (char)q0; o.y = (char)q1; o.z = (char)q2; o.w = (char)q3;
    ((char4*)(outq + (size_t)row * D_DIM))[t] = o;
    if (t == 0) outs[row] = amax / (127.0f * fmaxf(sqrtf(tot), 1e-8f));
}

__device__ __forceinline__ void gload_lds16(const void* g, void* l) {
    __builtin_amdgcn_global_load_lds(
        (const __attribute__((address_space(1))) void*)g,
        (__attribute__((address_space(3))) void*)l,
        16, 0, 0);
}

#define BAR()      asm volatile("s_barrier" ::: "memory")
#define LGKM0()    asm volatile("s_waitcnt lgkmcnt(0)" ::: "memory")
#define VMCNT0()   asm volatile("s_waitcnt vmcnt(0)" ::: "memory")
#define VMCNT63()  asm volatile("s_waitcnt vmcnt(63)" ::: "memory")

// LDS (128 KiB): A[p] at p*65536, B[p] at 32768 + p*65536; each 32 KB =
// [256 rows][128 i8], 8 x 16B slots/row, slot ^= row&7 (0-conflict).

// Stage one K-slice k (A half-pair + B half-pair) into parity PP.
__device__ __forceinline__ void stage_k(
        const signed char* __restrict__ sA, const signed char* __restrict__ sB,
        int k, int PP, char* lds0, int dstW) {
#pragma unroll
    for (int j = 0; j < 2; ++j) {
        gload_lds16(sA + (size_t)(j * 64) * D_DIM + k,
                    lds0 + PP * 65536 + j * 8192 + dstW);
        gload_lds16(sA + (size_t)(128 + j * 64) * D_DIM + k,
                    lds0 + PP * 65536 + 16384 + j * 8192 + dstW);
        gload_lds16(sB + (size_t)(j * 64) * D_DIM + k,
                    lds0 + 32768 + PP * 65536 + j * 8192 + dstW);
        gload_lds16(sB + (size_t)(128 + j * 64) * D_DIM + k,
                    lds0 + 32768 + PP * 65536 + 16384 + j * 8192 + dstW);
    }
}

// MODE 0: stage(t+1)->P^1, boundary vmcnt(0)+BAR
// MODE 1: no stage, boundary BAR only (k(t+1) pre-proven by the bridge)
// MODE 2: no stage, no boundary (final tile slice)
template<int P, int MODE>
__device__ __forceinline__ void ktile(
        int t, const signed char* __restrict__ sA,
        const signed char* __restrict__ sB,
        char* lds0, int dstW,
        const char* const (&pA)[2][2], const char* const (&pB)[2][2],
        i32x4 (&acc)[8][4])
{
    if constexpr (MODE == 0)
        stage_k(sA, sB, (t + 1) * BKt, P ^ 1, lds0, dstW);

    i32x4 af[8][2], bf[4][2];
#pragma unroll
    for (int m = 0; m < 8; ++m)
#pragma unroll
        for (int kk = 0; kk < 2; ++kk)
            af[m][kk] = *(const i32x4*)(pA[P][kk] + m * 2048);
#pragma unroll
    for (int n = 0; n < 4; ++n)
#pragma unroll
        for (int kk = 0; kk < 2; ++kk)
            bf[n][kk] = *(const i32x4*)(pB[P][kk] + n * 2048);

    __builtin_amdgcn_s_setprio(1);
#pragma unroll
    for (int m = 0; m < 8; ++m)
#pragma unroll
        for (int n = 0; n < 4; ++n)
#pragma unroll
            for (int kk = 0; kk < 2; ++kk)
                acc[m][n] = __builtin_amdgcn_mfma_i32_16x16x64_i8(
                    af[m][kk], bf[n][kk], acc[m][n], 0, 0, 0);
    __builtin_amdgcn_s_setprio(0);

    if constexpr (MODE == 0) { VMCNT0(); BAR(); }
    if constexpr (MODE == 1) { BAR(); }
}

__device__ __forceinline__ void epilogue(
        const i32x4 (&acc)[8][4], int crow0, int ccol0,
        const float* __restrict__ sx, const float* __restrict__ sb,
        float* __restrict__ Cg)
{
    float sbv[4];
#pragma unroll
    for (int n = 0; n < 4; ++n) sbv[n] = sb[ccol0 + n * 16];
#pragma unroll
    for (int m = 0; m < 8; ++m)
#pragma unroll
        for (int j = 0; j < 4; ++j) {
            const int row = crow0 + m * 16 + j;
            const float sav = sx[row];
#pragma unroll
            for (int n = 0; n < 4; ++n)
                Cg[(size_t)row * N_DIM + ccol0 + n * 16]
                    = (float)acc[m][n][j] * sav * sbv[n];
        }
}

__global__ __launch_bounds__(512, 1) void gemm256p(
        const signed char* __restrict__ A,
        const signed char* __restrict__ Bm,
        const float* __restrict__ sx,
        const float* __restrict__ sb,
        float* __restrict__ Cg)
{
    __shared__ char lds0[131072];  // 128 KiB

    // chunked XCD swizzle (grid 256, 32/XCD). XCD c: bn-pair c>>1,
    // bm in [32(c&1), 32(c&1)+32) -> per XCD: 32 A panels + 2 B cols (512KB L2)
    const int b = (int)blockIdx.x;
    const int s = (b & 7) * 32 + (b >> 3);   // bijective [0,256)
    const int bm  = s & 63;
    const int bn1 = (s >> 6) << 1;           // 0,2,4,6
    const int rowA0 = bm * BMt;
    const int rowB1 = bn1 * BNt;

    const int tid  = threadIdx.x;
    const int lane = tid & 63;
    const int wid  = tid >> 6;          // 0..7
    const int wr   = wid >> 2;          // 0..1 -> 128-row half
    const int wc   = wid & 3;           // 0..3 -> 64-col slice
    const int rl = lane & 15, ts = lane >> 4, r7 = rl & 7;

    // per-lane frag base ptrs (row&7 == rl&7; kk=1 slot = 4^(ts^r7))
    const int swz0 = ((ts ^ r7) << 4);
    const int swz1 = (((4 + ts) ^ r7) << 4);
    const int aRow = (wr * 128 + rl) * 128;
    const int bRow = (wc * 64 + rl) * 128;
    const char* pA[2][2];
    const char* pB[2][2];
#pragma unroll
    for (int p = 0; p < 2; ++p) {
        pA[p][0] = lds0 + p * 65536 + aRow + swz0;
        pA[p][1] = lds0 + p * 65536 + aRow + swz1;
        pB[p][0] = lds0 + 32768 + p * 65536 + bRow + swz0;
        pB[p][1] = lds0 + 32768 + p * 65536 + bRow + swz1;
    }

    // staging bases (source pre-swizzled, rule #21; 16 i8 per slot)
    const int gcol = (((tid & 7) ^ ((tid >> 3) & 7)) << 4);
    const int grow = (tid >> 3);
    const signed char* sA  = A  + (size_t)(rowA0 + grow) * D_DIM + gcol;
    const signed char* sB1 = Bm + (size_t)(rowB1 + grow) * D_DIM + gcol;
    const signed char* sB2 = sB1 + (size_t)BNt * D_DIM;
    const int dstW = wid * 1024;

    const int crow0 = rowA0 + wr * 128 + ts * 4;
    const int ccol1 = rowB1 + wc * 64 + rl;

    i32x4 acc[8][4] = {};

    // ---- tile1 prologue: stage k0 -> p0 ----
    stage_k(sA, sB1, 0, 0, lds0, dstW);
    VMCNT0();
    BAR();

    // ---- tile1 t0..t6 ----
#pragma unroll 1
    for (int t = 0; t < NKT - 2; t += 2) {
        ktile<0, 0>(t,     sA, sB1, lds0, dstW, pA, pB, acc);
        ktile<1, 0>(t + 1, sA, sB1, lds0, dstW, pA, pB, acc);
    }
    ktile<0, 0>(NKT - 2, sA, sB1, lds0, dstW, pA, pB, acc);

    // ---- BRIDGE: tile1 t7 (reads p1) + pre-stage tile2 k0/k1 + epilogue ----
    {
        i32x4 af[8][2], bf[4][2];
#pragma unroll
        for (int m = 0; m < 8; ++m)
#pragma unroll
            for (int kk = 0; kk < 2; ++kk)
                af[m][kk] = *(const i32x4*)(pA[1][kk] + m * 2048);
#pragma unroll
        for (int n = 0; n < 4; ++n)
#pragma unroll
            for (int kk = 0; kk < 2; ++kk)
                bf[n][kk] = *(const i32x4*)(pB[1][kk] + n * 2048);
        LGKM0();
        BAR();   // all waves' p0/p1 ds_reads drained -> LDS safe to overwrite

        stage_k(sA, sB2, 0,   0, lds0, dstW);   // tile2 k0 -> p0
        stage_k(sA, sB2, BKt, 1, lds0, dstW);   // tile2 k1 -> p1

        __builtin_amdgcn_s_setprio(1);
#pragma unroll
        for (int m = 0; m < 8; ++m)
#pragma unroll
            for (int n = 0; n < 4; ++n)
#pragma unroll
                for (int kk = 0; kk < 2; ++kk)
                    acc[m][n] = __builtin_amdgcn_mfma_i32_16x16x64_i8(
                        af[m][kk], bf[n][kk], acc[m][n], 0, 0, 0);
        __builtin_amdgcn_s_setprio(0);

        epilogue(acc, crow0, ccol1, sx, sb, Cg);  // tile1 C-stores (after DMAs)

        VMCNT63();   // <=63 outstanding (HW cap) => the 16 older DMAs retired
        BAR();       // every wave's DMAs proven -> tile2 may read p0/p1
    }

    // ---- tile2 ----
#pragma unroll
    for (int m = 0; m < 8; ++m)
#pragma unroll
        for (int n = 0; n < 4; ++n)
            acc[m][n] = (i32x4){0, 0, 0, 0};

    ktile<0, 1>(0, sA, sB2, lds0, dstW, pA, pB, acc);   // k0/k1 pre-proven
#pragma unroll 1
    for (int t = 1; t < NKT - 1; t += 2) {
        ktile<1, 0>(t,     sA, sB2, lds0, dstW, pA, pB, acc);
        ktile<0, 0>(t + 1, sA, sB2, lds0, dstW, pA, pB, acc);
    }
    ktile<1, 2>(NKT - 1, sA, sB2, lds0, dstW, pA, pB, acc);

    epilogue(acc, crow0, ccol1 + BNt, sx, sb, Cg);      // tile2 C-stores
}

extern "C" void kernel_launch(void* const* d_in, const int* in_sizes, int n_in,
                              void* d_out, int out_size, void* d_ws, size_t ws_size,
                              hipStream_t stream) {
    const float* x = (const float*)d_in[0];   // [B, D]
    const float* a = (const float*)d_in[1];   // [C, D]
    float* out = (float*)d_out;               // [B, C]

    const int Bn = in_sizes[0] / D_DIM;  // 16384
    const int Cn = in_sizes[1] / D_DIM;  // 2048

    signed char* xq = (signed char*)d_ws;                      // [B][D] i8
    signed char* aq = xq + (size_t)Bn * D_DIM;                 // [C][D] i8
    float* sx = (float*)(aq + (size_t)Cn * D_DIM);             // [B] f32
    float* sa = sx + Bn;                                       // [C] f32

    quant_rows<<<Bn + Cn, 256, 0, stream>>>(x, a, xq, aq, sx, sa, Bn);

    const int grid = (Bn / BMt) * (Cn / BNt) / 2;  // 256 persistent blocks
    gemm256p<<<grid, 512, 0, stream>>>(xq, aq, sx, sa, out);
}

// Round 20
// 69.202 us; speedup vs baseline: 1.4675x; 1.2722x over previous
//
#include <hip/hip_runtime.h>
#include <stdint.h>

// out[b,c] = <x_b/||x_b||, a_c/||a_c||>, B=16384, C=2048, D=1024, fp32 in/out.
// R20 = R16 REVERT (best verified: 69.3 us, absmax 1.95e-3).
//   Pass 1: per row ss=sum(x^2), amax=max|x|; q = round(127 x/amax) i8;
//           scale s = amax/(127*max(sqrt(ss),1e-8)). out = i32dot * s_x * s_a
//           (exact-integer MFMA: quantization is the only error source).
//   Pass 2: i8 MFMA GEMM, 256x256 tile, BK=128 i8 (128 B rows, byte-identical
//           geometry to the proven bf16 BK=64 tile: row&7 XOR slot swizzle,
//           0 bank conflicts), NKT=8, mfma_i32_16x16x64_i8 (2x bf16 rate,
//           half the LDS/staging bytes), free-run tile: stage 8 DMA ->
//           24 ds_read_b128 -> 64 MFMA -> vmcnt(0) -> barrier.
//   Race rule: stage targets parity P^1 only (readers drained at previous
//   barrier); boundary is vmcnt -> barrier -> read. XCD-chunked grid.
//   R17(2blk/CU)/R18(B-from-L2+nt)/R19(persistent bridge) all regressed vs
//   this structure -- see session ledger; this is the measured plateau.

#define D_DIM 1024
#define N_DIM 2048
#define BMt 256
#define BNt 256
#define BKt 128     // i8 elements per K-tile (128 B rows)
#define NKT 8       // D_DIM / BKt

typedef int   i32x4 __attribute__((ext_vector_type(4)));
typedef float f32x4 __attribute__((ext_vector_type(4)));

// One block per row (X rows then A rows): 256 threads x float4 = 1024 floats.
// Outputs: i8 quantized row + f32 scale per row.
__global__ __launch_bounds__(256) void quant_rows(
        const float* __restrict__ x, const float* __restrict__ a,
        char* __restrict__ xq, char* __restrict__ aq,
        float* __restrict__ sx, float* __restrict__ sa, int Bn) {
    const int blk = blockIdx.x;
    const float* in = (blk < Bn) ? x : a;
    char* outq      = (blk < Bn) ? xq : aq;
    float* outs     = (blk < Bn) ? sx : sa;
    const int row = (blk < Bn) ? blk : blk - Bn;
    const int t = threadIdx.x;
    const float4 v = ((const float4*)(in + (size_t)row * D_DIM))[t];
    float ss = v.x * v.x + v.y * v.y + v.z * v.z + v.w * v.w;
    float mx = fmaxf(fmaxf(fabsf(v.x), fabsf(v.y)), fmaxf(fabsf(v.z), fabsf(v.w)));
#pragma unroll
    for (int o = 1; o < 64; o <<= 1) {
        ss += __shfl_xor(ss, o);
        mx = fmaxf(mx, __shfl_xor(mx, o));
    }
    __shared__ float redS[4], redM[4];
    if ((t & 63) == 0) { redS[t >> 6] = ss; redM[t >> 6] = mx; }
    __syncthreads();
    const float tot  = redS[0] + redS[1] + redS[2] + redS[3];
    const float amax = fmaxf(fmaxf(redM[0], redM[1]), fmaxf(redM[2], redM[3]));
    const float inv  = (amax > 0.0f) ? (127.0f / amax) : 0.0f;
    int q0 = __float2int_rn(v.x * inv), q1 = __float2int_rn(v.y * inv);
    int q2 = __float2int_rn(v.z * inv), q3 = __float2int_rn(v.w * inv);
    q0 = min(127, max(-127, q0)); q1 = min(127, max(-127, q1));
    q2 = min(127, max(-127, q2)); q3 = min(127, max(-127, q3));
    char4 o; o.x = (char)q0; o.y = (char)q1; o.z = (char)q2; o.w = (char)q3;
    ((char4*)(outq + (size_t)row * D_DIM))[t] = o;
    if (t == 0) outs[row] = amax / (127.0f * fmaxf(sqrtf(tot), 1e-8f));
}

__device__ __forceinline__ void gload_lds16(const void* g, void* l) {
    __builtin_amdgcn_global_load_lds(
        (const __attribute__((address_space(1))) void*)g,
        (__attribute__((address_space(3))) void*)l,
        16, 0, 0);
}

#define BAR()     asm volatile("s_barrier" ::: "memory")
#define VMCNT0()  asm volatile("s_waitcnt vmcnt(0)" ::: "memory")

// LDS (128 KiB): A[p] at p*65536, B[p] at 32768 + p*65536; each region 32 KB =
// [256 rows][128 i8], 128 B/row, 8 x 16B slots, slot ^= row&7 (0-conflict).
template<int P, bool STAGE>
__device__ __forceinline__ void ktile(
        int t,
        const unsigned char* __restrict__ sA,   // A + rowA0*D + voff (per-lane)
        const unsigned char* __restrict__ sB,
        char* lds0, int dstW,                   // wid*1024 (byte)
        const char* const (&pA)[2][2], const char* const (&pB)[2][2],
        i32x4 (&acc)[8][4])
{
    // ---- stage all 8 half-tile DMAs for t+1 first ----
    if constexpr (STAGE) {
        const int k1 = (t + 1) * BKt;
#pragma unroll
        for (int j = 0; j < 2; ++j) {
            gload_lds16(sA + (size_t)(j * 64) * D_DIM + k1,
                        lds0 + (P ^ 1) * 65536 + j * 8192 + dstW);
            gload_lds16(sA + (size_t)(128 + j * 64) * D_DIM + k1,
                        lds0 + (P ^ 1) * 65536 + 16384 + j * 8192 + dstW);
            gload_lds16(sB + (size_t)(j * 64) * D_DIM + k1,
                        lds0 + 32768 + (P ^ 1) * 65536 + j * 8192 + dstW);
            gload_lds16(sB + (size_t)(128 + j * 64) * D_DIM + k1,
                        lds0 + 32768 + (P ^ 1) * 65536 + 16384 + j * 8192 + dstW);
        }
    }

    // ---- 24 fragment reads (parity P), conflict-free ----
    i32x4 af[8][2], bf[4][2];
#pragma unroll
    for (int m = 0; m < 8; ++m)
#pragma unroll
        for (int kk = 0; kk < 2; ++kk)
            af[m][kk] = *(const i32x4*)(pA[P][kk] + m * 2048);
#pragma unroll
    for (int n = 0; n < 4; ++n)
#pragma unroll
        for (int kk = 0; kk < 2; ++kk)
            bf[n][kk] = *(const i32x4*)(pB[P][kk] + n * 2048);

    // ---- 64 MFMA i8 K=64 (2 K-slices of the 128-K tile) ----
    __builtin_amdgcn_s_setprio(1);
#pragma unroll
    for (int m = 0; m < 8; ++m)
#pragma unroll
        for (int n = 0; n < 4; ++n)
#pragma unroll
            for (int kk = 0; kk < 2; ++kk)
                acc[m][n] = __builtin_amdgcn_mfma_i32_16x16x64_i8(
                    af[m][kk], bf[n][kk], acc[m][n], 0, 0, 0);
    __builtin_amdgcn_s_setprio(0);

    if constexpr (STAGE) {
        VMCNT0();   // my DMAs landed
        BAR();      // all waves' landed -> next tile may read
    }
}

__global__ __launch_bounds__(512, 2) void gemm256(
        const unsigned char* __restrict__ A,
        const unsigned char* __restrict__ Bm,
        const float* __restrict__ sx,
        const float* __restrict__ sb,
        float* __restrict__ Cg)
{
    __shared__ char lds0[131072];  // 128 KiB

    const int nwg = gridDim.x;          // 512
    const int cpx = nwg >> 3;           // 64
    const int wg  = ((int)blockIdx.x & 7) * cpx + ((int)blockIdx.x >> 3);
    const int bm  = wg >> 3;            // 0..63
    const int bn  = wg & 7;             // 0..7
    const int rowA0 = bm * BMt;
    const int rowB0 = bn * BNt;

    const int tid  = threadIdx.x;
    const int lane = tid & 63;
    const int wid  = tid >> 6;          // 0..7
    const int wr   = wid >> 2;          // 0..1 -> 128-row half
    const int wc   = wid & 3;           // 0..3 -> 64-col slice
    const int rl = lane & 15, ts = lane >> 4, r7 = rl & 7;

    // per-lane frag base ptrs (slot = kk*4+ts, byte-identical to bf16 BK=64)
    const int swz0 = ((ts ^ r7) << 4);
    const int swz1 = (((4 + ts) ^ r7) << 4);
    const int aRow = (wr * 128 + rl) * 128;
    const int bRow = (wc * 64 + rl) * 128;
    const char* pA[2][2];
    const char* pB[2][2];
#pragma unroll
    for (int p = 0; p < 2; ++p) {
        pA[p][0] = lds0 + p * 65536 + aRow + swz0;
        pA[p][1] = lds0 + p * 65536 + aRow + swz1;
        pB[p][0] = lds0 + 32768 + p * 65536 + bRow + swz0;
        pB[p][1] = lds0 + 32768 + p * 65536 + bRow + swz1;
    }

    // staging bases: row = tid>>3 (64 rows per 8KB slab), 16B slot = tid&7,
    // source col pre-swizzled (rule #21); 16 i8 elements per slot.
    const int gcol = (((tid & 7) ^ ((tid >> 3) & 7)) << 4);
    const int grow = (tid >> 3);
    const unsigned char* sA = A  + (size_t)(rowA0 + grow) * D_DIM + gcol;
    const unsigned char* sB = Bm + (size_t)(rowB0 + grow) * D_DIM + gcol;
    const int dstW = wid * 1024;

    i32x4 acc[8][4] = {};

    // prologue: stage tile 0 (parity 0); vmcnt(0) -> barrier
#pragma unroll
    for (int j = 0; j < 2; ++j) {
        gload_lds16(sA + (size_t)(j * 64) * D_DIM,        lds0 + j * 8192 + dstW);
        gload_lds16(sA + (size_t)(128 + j * 64) * D_DIM,  lds0 + 16384 + j * 8192 + dstW);
        gload_lds16(sB + (size_t)(j * 64) * D_DIM,        lds0 + 32768 + j * 8192 + dstW);
        gload_lds16(sB + (size_t)(128 + j * 64) * D_DIM,  lds0 + 32768 + 16384 + j * 8192 + dstW);
    }
    VMCNT0();
    BAR();

#pragma unroll 1
    for (int t = 0; t < NKT - 2; t += 2) {
        ktile<0, true>(t,     sA, sB, lds0, dstW, pA, pB, acc);
        ktile<1, true>(t + 1, sA, sB, lds0, dstW, pA, pB, acc);
    }
    ktile<0, true >(NKT - 2, sA, sB, lds0, dstW, pA, pB, acc);
    ktile<1, false>(NKT - 1, sA, sB, lds0, dstW, pA, pB, acc);

    // epilogue: C/D layout col=lane&15, row=(lane>>4)*4+j (dtype-independent);
    // out = float(acc) * sx[row] * sb[col]
    const int crow0 = rowA0 + wr * 128 + ts * 4;
    const int ccol0 = rowB0 + wc * 64 + rl;
    float sbv[4];
#pragma unroll
    for (int n = 0; n < 4; ++n) sbv[n] = sb[ccol0 + n * 16];
#pragma unroll
    for (int m = 0; m < 8; ++m)
#pragma unroll
        for (int j = 0; j < 4; ++j) {
            const int row = crow0 + m * 16 + j;
            const float sav = sx[row];
#pragma unroll
            for (int n = 0; n < 4; ++n)
                Cg[(size_t)row * N_DIM + ccol0 + n * 16]
                    = (float)acc[m][n][j] * sav * sbv[n];
        }
}

extern "C" void kernel_launch(void* const* d_in, const int* in_sizes, int n_in,
                              void* d_out, int out_size, void* d_ws, size_t ws_size,
                              hipStream_t stream) {
    const float* x = (const float*)d_in[0];   // [B, D]
    const float* a = (const float*)d_in[1];   // [C, D]
    float* out = (float*)d_out;               // [B, C]

    const int Bn = in_sizes[0] / D_DIM;  // 16384
    const int Cn = in_sizes[1] / D_DIM;  // 2048

    char*  xq = (char*)d_ws;                                   // [B][D] i8
    char*  aq = xq + (size_t)Bn * D_DIM;                       // [C][D] i8
    float* sx = (float*)(aq + (size_t)Cn * D_DIM);             // [B] f32
    float* sa = sx + Bn;                                       // [C] f32

    quant_rows<<<Bn + Cn, 256, 0, stream>>>(x, a, xq, aq, sx, sa, Bn);

    const int grid = (Bn / BMt) * (Cn / BNt);  // 64 * 8 = 512
    gemm256<<<grid, 512, 0, stream>>>((const unsigned char*)xq,
                                      (const unsigned char*)aq, sx, sa, out);
}